// Round 2
// baseline (948.514 us; speedup 1.0000x reference)
//
#include <hip/hip_runtime.h>
#include <math.h>

#define L     8192
#define DCH   768
#define BATCH 4
#define M     8192   // complex FFT size (real FFT size 16384 via packing)
#define MLOG  13

__device__ __forceinline__ float2 cmul(float2 a, float2 b) {
  return make_float2(a.x * b.x - a.y * b.y, a.x * b.y + a.y * b.x);
}

__device__ __forceinline__ int brev13(int n) {
  return (int)(__brev((unsigned)n) >> 19);
}

__device__ __forceinline__ float2 twiddle(float ang) {  // exp(i*ang)
  float s, c;
  __sincosf(ang, &s, &c);
  return make_float2(c, s);
}

// In-place DIT radix-2 FFT of M complex values in LDS.
// Input must be in bit-reversed order; output is natural order.
// Includes leading sync (covers caller's scatter) and trailing sync.
__device__ void fft_m(float2* A, int tid) {
  const float nTwoPiOverM = -6.2831853071795864769f / (float)M;
  for (int s = 0; s < MLOG; ++s) {
    __syncthreads();
    int half = 1 << s;
    #pragma unroll 4
    for (int i = 0; i < 16; ++i) {
      int j = tid + (i << 8);          // butterfly id 0..4095
      int pos = j & (half - 1);
      int i0 = ((j >> s) << (s + 1)) | pos;
      float ang = nTwoPiOverM * (float)(pos << (MLOG - 1 - s));
      float2 w = twiddle(ang);
      float2 a = A[i0];
      float2 b = A[i0 + half];
      float2 bw = cmul(b, w);
      A[i0]        = make_float2(a.x + bw.x, a.y + bw.y);
      A[i0 + half] = make_float2(a.x - bw.x, a.y - bw.y);
    }
  }
  __syncthreads();
}

// ---------------- Kernel 1: implicit-filter MLP -> S[L][64] ----------------
__global__ __launch_bounds__(256) void mlp_kernel(
    const float* __restrict__ w0, const float* __restrict__ b0,
    const float* __restrict__ w1, const float* __restrict__ b1,
    const float* __restrict__ freq, float* __restrict__ S) {
  __shared__ float w1s[64 * 64];
  __shared__ float w0s[3 * 64];
  __shared__ float b0s[64], b1s[64], fqs[64];
  int tid = threadIdx.x;
  for (int i = tid; i < 4096; i += 256) w1s[i] = w1[i];
  if (tid < 192) w0s[tid] = w0[tid];
  if (tid < 64) { b0s[tid] = b0[tid]; b1s[tid] = b1[tid]; fqs[tid] = freq[tid]; }
  __syncthreads();

  int n = blockIdx.x * 256 + tid;
  float t  = (float)n / (float)(L - 1);
  float th = 1e-4f * (6.2831853071795864769f * (float)n / (float)L);
  float z1 = cosf(th);
  float z2 = -sinf(th);

  float h0[64];
  #pragma unroll
  for (int j = 0; j < 64; ++j) {
    float a = t * w0s[j] + z1 * w0s[64 + j] + z2 * w0s[128 + j] + b0s[j];
    h0[j] = sinf(fqs[j] * a);
  }
  float* Srow = S + (size_t)n * 64;
  for (int j = 0; j < 64; ++j) {
    float acc = b1s[j];
    #pragma unroll
    for (int i = 0; i < 64; ++i) acc += h0[i] * w1s[i * 64 + j];
    Srow[j] = sinf(fqs[j] * acc);
  }
}

// ------- Kernel 2: k_t[d][n] = (S[n]·w2[:,d] + b2[d]) * exp(-t|delta_d|) -------
__global__ __launch_bounds__(256) void kfilter_kernel(
    const float* __restrict__ S, const float* __restrict__ w2,
    const float* __restrict__ b2, const float* __restrict__ deltas,
    float* __restrict__ kt) {
  __shared__ float Ss[64][65];
  int tid = threadIdx.x;
  int n0 = blockIdx.x * 64;
  int d0 = blockIdx.y * 4;
  #pragma unroll
  for (int i = 0; i < 16; ++i) {
    int idx = tid + i * 256;
    Ss[idx >> 6][idx & 63] = S[(size_t)n0 * 64 + idx];
  }
  __syncthreads();
  int nn = tid & 63, dd = tid >> 6;
  int d = d0 + dd, n = n0 + nn;
  float acc = b2[d];
  #pragma unroll 8
  for (int j = 0; j < 64; ++j) acc += Ss[nn][j] * w2[j * DCH + d];
  float t = (float)n / (float)(L - 1);
  float decay = expf(-t * fabsf(deltas[d]));
  kt[(size_t)d * L + n] = acc * (decay + 0.0f);  // SHIFT = 0
}

// ---------------- tiled transpose src[R][C] -> dst[C][R] (+ optional bias[r]) ----------------
__global__ __launch_bounds__(256) void transpose_kernel(
    const float* __restrict__ src, float* __restrict__ dst,
    int R, int C, const float* __restrict__ bias) {
  __shared__ float tile[32][33];
  int c0 = blockIdx.x * 32, r0 = blockIdx.y * 32;
  int tx = threadIdx.x, ty = threadIdx.y;
  #pragma unroll
  for (int k = 0; k < 4; ++k) {
    int r = r0 + ty + k * 8;
    tile[ty + k * 8][tx] = src[(size_t)r * C + c0 + tx];
  }
  __syncthreads();
  float bv = (bias != nullptr) ? bias[r0 + tx] : 0.0f;
  #pragma unroll
  for (int k = 0; k < 4; ++k) {
    int c = c0 + ty + k * 8;
    dst[(size_t)c * R + r0 + tx] = tile[tx][ty + k * 8] + bv;
  }
}

// ---------------- Kernel 4: filter FFT -> Kf[d][k] = rfft(k_d,16384)/16384 ----------------
// Nyquist (bin 8192, real) packed into bin0.y (bin0 also real).
__global__ __launch_bounds__(256) void fftk_kernel(
    const float* __restrict__ kt, float2* __restrict__ Kf) {
  __shared__ float2 A[M];
  int tid = threadIdx.x;
  int d = blockIdx.x;
  const float2* src = (const float2*)(kt + (size_t)d * L);
  #pragma unroll
  for (int i = 0; i < 16; ++i) {
    int n = tid + (i << 8);
    A[brev13(n)] = src[n];                    // z[n] = k[2n] + i k[2n+1], n<4096
  }
  #pragma unroll
  for (int i = 0; i < 16; ++i) {
    int n = 4096 + tid + (i << 8);
    A[brev13(n)] = make_float2(0.f, 0.f);     // zero padding
  }
  fft_m(A, tid);

  float2* Kfd = Kf + (size_t)d * M;
  const float sc = 1.0f / 16384.0f;
  #pragma unroll
  for (int i = 0; i < 16; ++i) {
    int k = tid + (i << 8);
    if (k == 0) {
      float2 Z0 = A[0];
      Kfd[0] = make_float2((Z0.x + Z0.y) * sc, (Z0.x - Z0.y) * sc);  // (U0, U_M)
      float2 Z4 = A[4096];
      Kfd[4096] = make_float2(Z4.x * sc, -Z4.y * sc);                 // conj(Z[M/2])
    } else {
      int jj = M - k;
      float2 Zk = A[k], Zj = A[jj];
      float2 Ze = make_float2(0.5f * (Zk.x + Zj.x), 0.5f * (Zk.y - Zj.y));
      float2 Zo = make_float2(0.5f * (Zk.y + Zj.y), -0.5f * (Zk.x - Zj.x));
      float ang = -6.2831853071795864769f * (float)k * (1.0f / 16384.0f);
      float2 W = twiddle(ang);
      float2 WZo = cmul(W, Zo);
      Kfd[k]  = make_float2((Ze.x + WZo.x) * sc, (Ze.y + WZo.y) * sc);
      Kfd[jj] = make_float2((Ze.x - WZo.x) * sc, -(Ze.y - WZo.y) * sc);
    }
  }
}

// ---------------- Kernel 5: per-channel FFT conv (in-place over one batch slab xt[D][L]) ----------------
__global__ __launch_bounds__(256) void conv_kernel(
    float* __restrict__ xt, const float2* __restrict__ Kf) {
  __shared__ float2 A[M];
  int tid = threadIdx.x;
  int d = blockIdx.x;
  float2* ch = (float2*)(xt + (size_t)d * L);

  #pragma unroll
  for (int i = 0; i < 16; ++i) {
    int n = tid + (i << 8);
    A[brev13(n)] = ch[n];                     // z[n] = x[2n] + i x[2n+1], n<4096
  }
  #pragma unroll
  for (int i = 0; i < 16; ++i) {
    int n = 4096 + tid + (i << 8);
    A[brev13(n)] = make_float2(0.f, 0.f);
  }
  fft_m(A, tid);

  // unpack -> multiply by Kf -> repack (conjugated for inverse via conj trick)
  const float2* Kfd = Kf + (size_t)d * M;
  float2 outk[16], outj[16];
  #pragma unroll
  for (int i = 0; i < 16; ++i) {
    int k = tid + (i << 8);
    if (k == 0) {
      float2 Z0 = A[0];
      float U0 = Z0.x + Z0.y, UM = Z0.x - Z0.y;
      float2 C0 = Kfd[0];
      float V0 = U0 * C0.x, VM = UM * C0.y;
      outk[i] = make_float2(0.5f * (V0 + VM), -0.5f * (V0 - VM));  // conj(Z'[0])
      float2 Z4 = A[4096];
      float2 U4 = make_float2(Z4.x, -Z4.y);
      outj[i] = cmul(U4, Kfd[4096]);                                // conj(Z'[M/2]) = V
    } else {
      int jj = M - k;
      float2 Zk = A[k], Zj = A[jj];
      float2 Ze = make_float2(0.5f * (Zk.x + Zj.x), 0.5f * (Zk.y - Zj.y));
      float2 Zo = make_float2(0.5f * (Zk.y + Zj.y), -0.5f * (Zk.x - Zj.x));
      float ang = -6.2831853071795864769f * (float)k * (1.0f / 16384.0f);
      float2 W = twiddle(ang);
      float2 WZo = cmul(W, Zo);
      float2 Uk = make_float2(Ze.x + WZo.x, Ze.y + WZo.y);
      float2 Uj = make_float2(Ze.x - WZo.x, -(Ze.y - WZo.y));
      float2 Vk = cmul(Uk, Kfd[k]);
      float2 Vj = cmul(Uj, Kfd[jj]);
      float2 Fe = make_float2(0.5f * (Vk.x + Vj.x), 0.5f * (Vk.y - Vj.y));
      float2 G  = make_float2(0.5f * (Vk.x - Vj.x), 0.5f * (Vk.y + Vj.y));
      float2 Fo = cmul(make_float2(W.x, -W.y), G);
      outk[i] = make_float2(Fe.x - Fo.y, -(Fe.y + Fo.x));  // conj(Z'[k])
      outj[i] = make_float2(Fe.x + Fo.y, Fe.y - Fo.x);     // conj(Z'[M-k])
    }
  }
  __syncthreads();
  #pragma unroll
  for (int i = 0; i < 16; ++i) {
    int k = tid + (i << 8);
    int jj = (k == 0) ? 4096 : (M - k);
    A[brev13(k)]  = outk[i];
    A[brev13(jj)] = outj[i];
  }
  fft_m(A, tid);

  // z'[n] = conj(F[n])/M ; y[2n] = Re, y[2n+1] = Im ; only n<4096 needed
  const float inv = 1.0f / (float)M;
  #pragma unroll
  for (int i = 0; i < 16; ++i) {
    int n = tid + (i << 8);
    float2 F = A[n];
    ch[n] = make_float2(F.x * inv, -F.y * inv);
  }
}

extern "C" void kernel_launch(void* const* d_in, const int* in_sizes, int n_in,
                              void* d_out, int out_size, void* d_ws, size_t ws_size,
                              hipStream_t stream) {
  const float* x      = (const float*)d_in[0];
  const float* w0     = (const float*)d_in[1];
  const float* b0     = (const float*)d_in[2];
  const float* w1     = (const float*)d_in[3];
  const float* b1     = (const float*)d_in[4];
  const float* w2     = (const float*)d_in[5];
  const float* b2     = (const float*)d_in[6];
  const float* freq   = (const float*)d_in[7];
  const float* deltas = (const float*)d_in[8];
  const float* bias   = (const float*)d_in[9];
  float* out = (float*)d_out;

  // workspace layout (74 MB total; previous round's 170 MB suspected > ws_size):
  //   [S: L*64 f32 = 2 MB][Kf: D*M float2 = 48 MB][slab: D*L f32 = 24 MB]
  // `slab` holds kt (time-domain filters) until fftk consumes it, then is
  // reused per batch as the transposed-x buffer (stream order makes this safe).
  float*  S    = (float*)d_ws;
  float2* Kf   = (float2*)(S + (size_t)L * 64);
  float*  slab = (float*)(Kf + (size_t)DCH * M);

  mlp_kernel<<<32, 256, 0, stream>>>(w0, b0, w1, b1, freq, S);
  kfilter_kernel<<<dim3(128, 192), 256, 0, stream>>>(S, w2, b2, deltas, slab);
  fftk_kernel<<<DCH, 256, 0, stream>>>(slab, Kf);

  for (int b = 0; b < BATCH; ++b) {
    const float* xb = x + (size_t)b * L * DCH;
    float* ob = out + (size_t)b * L * DCH;
    // x[b]: [L][D] -> slab: [D][L]
    transpose_kernel<<<dim3(DCH / 32, L / 32), dim3(32, 8), 0, stream>>>(
        xb, slab, L, DCH, nullptr);
    conv_kernel<<<DCH, 256, 0, stream>>>(slab, Kf);
    // slab: [D][L] -> out[b]: [L][D], + bias[d]
    transpose_kernel<<<dim3(L / 32, DCH / 32), dim3(32, 8), 0, stream>>>(
        slab, ob, DCH, L, bias);
  }
}

// Round 3
// 815.507 us; speedup vs baseline: 1.1631x; 1.1631x over previous
//
#include <hip/hip_runtime.h>
#include <math.h>

#define L     8192
#define DCH   768
#define BATCH 4
#define M     8192   // complex FFT size (real FFT size 16384 via packing)
#define MLOG  13

// LDS bank swizzle: bijective, bounds all FFT-round patterns to <=4-way
#define PHYS(i) ((i) ^ (((i) >> 4) & 15))

__device__ __forceinline__ float2 cmul(float2 a, float2 b) {
  return make_float2(a.x * b.x - a.y * b.y, a.x * b.y + a.y * b.x);
}
__device__ __forceinline__ float2 cadd(float2 a, float2 b) {
  return make_float2(a.x + b.x, a.y + b.y);
}
__device__ __forceinline__ float2 csub(float2 a, float2 b) {
  return make_float2(a.x - b.x, a.y - b.y);
}
__device__ __forceinline__ float2 csq(float2 a) {
  return make_float2(a.x * a.x - a.y * a.y, 2.0f * a.x * a.y);
}
__device__ __forceinline__ float2 conj2(float2 a) { return make_float2(a.x, -a.y); }

__device__ __forceinline__ int brev13(int n) {
  return (int)(__brev((unsigned)n) >> 19);
}

__device__ __forceinline__ float2 twiddle(float ang) {  // exp(i*ang)
  float s, c;
  __sincosf(ang, &s, &c);
  return make_float2(c, s);
}

#define C8  0.70710678118654752f
#define C16 0.92387953251128676f
#define S16 0.38268343236508977f
__device__ const float2 W16C[8] = {
  {1.f, 0.f}, {C16, -S16}, {C8, -C8}, {S16, -C16},
  {0.f, -1.f}, {-S16, -C16}, {-C8, -C8}, {-C16, -S16}};
__device__ const float2 W8C[4] = {{1.f, 0.f}, {C8, -C8}, {0.f, -1.f}, {-C8, -C8}};

// ---- radix-8 DIF butterfly (3 stages, descending): twiddle on difference ----
// verified vs DFT-8 (delta test, incl. bitrev output order)
__device__ __forceinline__ void r8_dif(float2 x[8], float2 w, float2 w2, float2 w4) {
  float2 y0 = cadd(x[0], x[4]), t0 = csub(x[0], x[4]);
  float2 y1 = cadd(x[1], x[5]), t1 = csub(x[1], x[5]);
  float2 y2 = cadd(x[2], x[6]), t2 = csub(x[2], x[6]);
  float2 y3 = cadd(x[3], x[7]), t3 = csub(x[3], x[7]);
  float2 y4 = cmul(t0, w);
  float2 y5 = cmul(t1, cmul(w, W8C[1]));
  float2 y6 = cmul(t2, cmul(w, W8C[2]));
  float2 y7 = cmul(t3, cmul(w, W8C[3]));
  float2 w2n = make_float2(w2.y, -w2.x);   // w2 * (-i)
  float2 z0 = cadd(y0, y2), z2 = cmul(csub(y0, y2), w2);
  float2 z1 = cadd(y1, y3), z3 = cmul(csub(y1, y3), w2n);
  float2 z4 = cadd(y4, y6), z6 = cmul(csub(y4, y6), w2);
  float2 z5 = cadd(y5, y7), z7 = cmul(csub(y5, y7), w2n);
  x[0] = cadd(z0, z1); x[1] = cmul(csub(z0, z1), w4);
  x[2] = cadd(z2, z3); x[3] = cmul(csub(z2, z3), w4);
  x[4] = cadd(z4, z5); x[5] = cmul(csub(z4, z5), w4);
  x[6] = cadd(z6, z7); x[7] = cmul(csub(z6, z7), w4);
}

// ---- radix-8 DIT butterfly (3 stages, ascending): twiddle before add ----
__device__ __forceinline__ void r8_dit(float2 x[8], float2 w, float2 w2, float2 w4) {
  float2 a1 = cmul(x[1], w4), a3 = cmul(x[3], w4);
  float2 a5 = cmul(x[5], w4), a7 = cmul(x[7], w4);
  float2 y0 = cadd(x[0], a1), y1 = csub(x[0], a1);
  float2 y2 = cadd(x[2], a3), y3 = csub(x[2], a3);
  float2 y4 = cadd(x[4], a5), y5 = csub(x[4], a5);
  float2 y6 = cadd(x[6], a7), y7 = csub(x[6], a7);
  float2 w2n = make_float2(w2.y, -w2.x);
  float2 b2 = cmul(y2, w2), b3 = cmul(y3, w2n);
  float2 b6 = cmul(y6, w2), b7 = cmul(y7, w2n);
  float2 z0 = cadd(y0, b2), z2 = csub(y0, b2);
  float2 z1 = cadd(y1, b3), z3 = csub(y1, b3);
  float2 z4 = cadd(y4, b6), z6 = csub(y4, b6);
  float2 z5 = cadd(y5, b7), z7 = csub(y5, b7);
  float2 c4 = cmul(z4, w);
  float2 c5 = cmul(z5, cmul(w, W8C[1]));
  float2 c6 = cmul(z6, cmul(w, W8C[2]));
  float2 c7 = cmul(z7, cmul(w, W8C[3]));
  x[0] = cadd(z0, c4); x[4] = csub(z0, c4);
  x[1] = cadd(z1, c5); x[5] = csub(z1, c5);
  x[2] = cadd(z2, c6); x[6] = csub(z2, c6);
  x[3] = cadd(z3, c7); x[7] = csub(z3, c7);
}

// ---- one LDS round of radix-8 groups (in-place, same-thread read/write) ----
template <int S, bool DIF>
__device__ __forceinline__ void r8_round(float2* A, int tid) {
  const int half = 1 << S;
  #pragma unroll
  for (int i = 0; i < 4; ++i) {
    int g = tid + (i << 8);
    int pos = g & (half - 1);
    int base = ((g >> S) << (S + 3)) | pos;
    float2 x[8];
    #pragma unroll
    for (int u = 0; u < 8; ++u) x[u] = A[PHYS(base + (u << S))];
    float2 w, w2, w4;
    if constexpr (S == 0) {
      w = make_float2(1.f, 0.f); w2 = w; w4 = w;
    } else {
      w = twiddle(-6.2831853071795864769f * (float)pos / (float)(8 << S));
      w2 = csq(w); w4 = csq(w2);
    }
    if constexpr (DIF) r8_dif(x, w, w2, w4); else r8_dit(x, w, w2, w4);
    #pragma unroll
    for (int u = 0; u < 8; ++u) A[PHYS(base + (u << S))] = x[u];
  }
}

// Forward DIF rounds over LDS: input = src (4096 nonzero float2, upper half zero)
// round1: radix-16 (stages 12..9) reading global directly, skipping zero half.
__device__ __forceinline__ void fwd_fft(float2* A, const float2* __restrict__ src,
                                        int tid) {
  #pragma unroll
  for (int j = 0; j < 2; ++j) {
    int pos = tid + (j << 8);
    float2 x[8], hi[8];
    #pragma unroll
    for (int u = 0; u < 8; ++u) x[u] = src[pos + (u << 9)];
    float2 v = twiddle(-6.2831853071795864769f * (float)pos / 8192.0f);
    float2 v2 = csq(v), v4 = csq(v2), v8 = csq(v4);
    #pragma unroll
    for (int u = 0; u < 8; ++u) hi[u] = cmul(x[u], cmul(v, W16C[u]));
    r8_dif(x, v2, v4, v8);
    r8_dif(hi, v2, v4, v8);
    #pragma unroll
    for (int u = 0; u < 8; ++u) A[PHYS(pos + (u << 9))] = x[u];
    #pragma unroll
    for (int u = 0; u < 8; ++u) A[PHYS(pos + ((u + 8) << 9))] = hi[u];
  }
  __syncthreads();
  r8_round<6, true>(A, tid);
  __syncthreads();
  r8_round<3, true>(A, tid);
  __syncthreads();
  r8_round<0, true>(A, tid);
  __syncthreads();
}

// ---------------- Kernel 1: implicit-filter MLP -> S[L][64] ----------------
__global__ __launch_bounds__(256) void mlp_kernel(
    const float* __restrict__ w0, const float* __restrict__ b0,
    const float* __restrict__ w1, const float* __restrict__ b1,
    const float* __restrict__ freq, float* __restrict__ S) {
  __shared__ float w1s[64 * 64];
  __shared__ float w0s[3 * 64];
  __shared__ float b0s[64], b1s[64], fqs[64];
  int tid = threadIdx.x;
  for (int i = tid; i < 4096; i += 256) w1s[i] = w1[i];
  if (tid < 192) w0s[tid] = w0[tid];
  if (tid < 64) { b0s[tid] = b0[tid]; b1s[tid] = b1[tid]; fqs[tid] = freq[tid]; }
  __syncthreads();

  int n = blockIdx.x * 256 + tid;
  float t  = (float)n / (float)(L - 1);
  float th = 1e-4f * (6.2831853071795864769f * (float)n / (float)L);
  float z1 = cosf(th);
  float z2 = -sinf(th);

  float h0[64];
  #pragma unroll
  for (int j = 0; j < 64; ++j) {
    float a = t * w0s[j] + z1 * w0s[64 + j] + z2 * w0s[128 + j] + b0s[j];
    h0[j] = sinf(fqs[j] * a);
  }
  float* Srow = S + (size_t)n * 64;
  for (int j = 0; j < 64; ++j) {
    float acc = b1s[j];
    #pragma unroll
    for (int i = 0; i < 64; ++i) acc += h0[i] * w1s[i * 64 + j];
    Srow[j] = sinf(fqs[j] * acc);
  }
}

// ------- Kernel 2: k_t[d][n] = (S[n]·w2[:,d] + b2[d]) * exp(-t|delta_d|) -------
__global__ __launch_bounds__(256) void kfilter_kernel(
    const float* __restrict__ S, const float* __restrict__ w2,
    const float* __restrict__ b2, const float* __restrict__ deltas,
    float* __restrict__ kt) {
  __shared__ float Ss[64][65];
  int tid = threadIdx.x;
  int n0 = blockIdx.x * 64;
  int d0 = blockIdx.y * 4;
  #pragma unroll
  for (int i = 0; i < 16; ++i) {
    int idx = tid + i * 256;
    Ss[idx >> 6][idx & 63] = S[(size_t)n0 * 64 + idx];
  }
  __syncthreads();
  int nn = tid & 63, dd = tid >> 6;
  int d = d0 + dd, n = n0 + nn;
  float acc = b2[d];
  #pragma unroll 8
  for (int j = 0; j < 64; ++j) acc += Ss[nn][j] * w2[j * DCH + d];
  float t = (float)n / (float)(L - 1);
  float decay = expf(-t * fabsf(deltas[d]));
  kt[(size_t)d * L + n] = acc * decay;  // SHIFT = 0
}

// ---------------- tiled transpose src[R][C] -> dst[C][R] (+ optional bias[r]) ----------------
__global__ __launch_bounds__(256) void transpose_kernel(
    const float* __restrict__ src, float* __restrict__ dst,
    int R, int C, const float* __restrict__ bias) {
  __shared__ float tile[32][33];
  int c0 = blockIdx.x * 32, r0 = blockIdx.y * 32;
  int tx = threadIdx.x, ty = threadIdx.y;
  #pragma unroll
  for (int k = 0; k < 4; ++k) {
    int r = r0 + ty + k * 8;
    tile[ty + k * 8][tx] = src[(size_t)r * C + c0 + tx];
  }
  __syncthreads();
  float bv = (bias != nullptr) ? bias[r0 + tx] : 0.0f;
  #pragma unroll
  for (int k = 0; k < 4; ++k) {
    int c = c0 + ty + k * 8;
    dst[(size_t)c * R + r0 + tx] = tile[tx][ty + k * 8] + bv;
  }
}

// ---- Kernel 4: filter FFT -> Kf_br[d][p] = rfft(k_d,16384)[br13(p)]/16384 ----
// p=0 packs (R[0], R[8192]) (both real).
__global__ __launch_bounds__(256) void fftk_kernel(
    const float* __restrict__ kt, float2* __restrict__ Kf) {
  __shared__ float2 A[M];
  int tid = threadIdx.x;
  int d = blockIdx.x;
  fwd_fft(A, (const float2*)(kt + (size_t)d * L), tid);

  float2* Kfd = Kf + (size_t)d * M;
  const float sc = 1.0f / 16384.0f;
  #pragma unroll
  for (int i = 0; i < 32; ++i) {
    int p = tid + (i << 8);
    if (p == 0) {
      float2 Z0 = A[PHYS(0)];
      Kfd[0] = make_float2(sc * (Z0.x + Z0.y), sc * (Z0.x - Z0.y));
    } else {
      int t = 31 - __clz(p);
      int q = (3 << t) - 1 - p;         // partner position (same dyadic block)
      float2 Zk = A[PHYS(p)], Zj = A[PHYS(q)];
      float2 Ze = make_float2(0.5f * (Zk.x + Zj.x), 0.5f * (Zk.y - Zj.y));
      float2 Zo = make_float2(0.5f * (Zk.y + Zj.y), -0.5f * (Zk.x - Zj.x));
      int k = brev13(p);
      float2 W = twiddle(-3.14159265358979323846f * (float)k / 8192.0f);
      float2 U = cadd(Ze, cmul(W, Zo));  // R_filt[k]
      Kfd[p] = make_float2(sc * U.x, sc * U.y);
    }
  }
}

// ---------------- Kernel 5: per-channel FFT conv (in-place over one batch slab xt[D][L]) ----------------
__global__ __launch_bounds__(256) void conv_kernel(
    float* __restrict__ xt, const float2* __restrict__ Kf) {
  __shared__ float2 A[M];
  int tid = threadIdx.x;
  int d = blockIdx.x;
  float2* ch = (float2*)(xt + (size_t)d * L);

  fwd_fft(A, ch, tid);

  // per-position pointwise: unpack -> *Kf -> repack, store conj for DIT-inverse
  const float2* Kfd = Kf + (size_t)d * M;
  float2 outv[32];
  #pragma unroll
  for (int i = 0; i < 32; ++i) {
    int p = tid + (i << 8);
    if (p == 0) {
      float2 Z0 = A[PHYS(0)];
      float U0 = Z0.x + Z0.y, UM = Z0.x - Z0.y;
      float2 C0 = Kfd[0];
      float V0 = U0 * C0.x, VM = UM * C0.y;
      outv[i] = make_float2(0.5f * (V0 + VM), -0.5f * (V0 - VM));
    } else {
      int t = 31 - __clz(p);
      int q = (3 << t) - 1 - p;
      float2 Zk = A[PHYS(p)], Zj = A[PHYS(q)];
      float2 Ze = make_float2(0.5f * (Zk.x + Zj.x), 0.5f * (Zk.y - Zj.y));
      float2 Zo = make_float2(0.5f * (Zk.y + Zj.y), -0.5f * (Zk.x - Zj.x));
      int k = brev13(p);
      float2 W = twiddle(-3.14159265358979323846f * (float)k / 8192.0f);
      float2 WZo = cmul(W, Zo);
      float2 Uk  = cadd(Ze, WZo);        // R_x[k]
      float2 Umc = csub(Ze, WZo);        // conj(R_x[M-k])
      float2 Ck = Kfd[p], Cj = Kfd[q];
      float2 Vk  = cmul(Uk, Ck);         // Y[k]
      float2 VjC = cmul(Umc, conj2(Cj)); // conj(Y[M-k])
      float2 Ye = make_float2(0.5f * (Vk.x + VjC.x), 0.5f * (Vk.y + VjC.y));
      float2 G  = make_float2(0.5f * (Vk.x - VjC.x), 0.5f * (Vk.y - VjC.y));
      float2 Yo = cmul(conj2(W), G);
      outv[i] = make_float2(Ye.x - Yo.y, -(Ye.y + Yo.x));  // conj(Z'[k])
    }
  }
  __syncthreads();   // all partner reads complete before overwriting
  #pragma unroll
  for (int i = 0; i < 32; ++i) {
    int p = tid + (i << 8);
    A[PHYS(p)] = outv[i];
  }
  __syncthreads();

  // inverse via DIT on conj'd spectrum (bitrev layout is exactly DIT input)
  r8_round<0, false>(A, tid);
  __syncthreads();
  r8_round<3, false>(A, tid);
  __syncthreads();
  r8_round<6, false>(A, tid);
  __syncthreads();

  // final radix-16 DIT (stages 9..12); only u<8 outputs needed (n < 4096)
  const float inv = 1.0f / (float)M;
  #pragma unroll
  for (int j = 0; j < 2; ++j) {
    int pos = tid + (j << 8);
    float2 xl[8], xh[8];
    #pragma unroll
    for (int u = 0; u < 8; ++u) xl[u] = A[PHYS(pos + (u << 9))];
    #pragma unroll
    for (int u = 0; u < 8; ++u) xh[u] = A[PHYS(pos + ((u + 8) << 9))];
    float2 v = twiddle(-6.2831853071795864769f * (float)pos / 8192.0f);
    float2 v2 = csq(v), v4 = csq(v2), v8 = csq(v4);
    r8_dit(xl, v2, v4, v8);
    r8_dit(xh, v2, v4, v8);
    #pragma unroll
    for (int u = 0; u < 8; ++u) {
      float2 F = cadd(xl[u], cmul(cmul(v, W16C[u]), xh[u]));
      ch[pos + (u << 9)] = make_float2(F.x * inv, -F.y * inv);
    }
  }
}

extern "C" void kernel_launch(void* const* d_in, const int* in_sizes, int n_in,
                              void* d_out, int out_size, void* d_ws, size_t ws_size,
                              hipStream_t stream) {
  const float* x      = (const float*)d_in[0];
  const float* w0     = (const float*)d_in[1];
  const float* b0     = (const float*)d_in[2];
  const float* w1     = (const float*)d_in[3];
  const float* b1     = (const float*)d_in[4];
  const float* w2     = (const float*)d_in[5];
  const float* b2     = (const float*)d_in[6];
  const float* freq   = (const float*)d_in[7];
  const float* deltas = (const float*)d_in[8];
  const float* bias   = (const float*)d_in[9];
  float* out = (float*)d_out;

  // workspace layout (74 MB): [S: 2 MB][Kf: 48 MB][slab: 24 MB]
  // slab = kt until fftk consumes it, then per-batch transposed-x buffer.
  float*  S    = (float*)d_ws;
  float2* Kf   = (float2*)(S + (size_t)L * 64);
  float*  slab = (float*)(Kf + (size_t)DCH * M);

  mlp_kernel<<<32, 256, 0, stream>>>(w0, b0, w1, b1, freq, S);
  kfilter_kernel<<<dim3(128, 192), 256, 0, stream>>>(S, w2, b2, deltas, slab);
  fftk_kernel<<<DCH, 256, 0, stream>>>(slab, Kf);

  for (int b = 0; b < BATCH; ++b) {
    const float* xb = x + (size_t)b * L * DCH;
    float* ob = out + (size_t)b * L * DCH;
    transpose_kernel<<<dim3(DCH / 32, L / 32), dim3(32, 8), 0, stream>>>(
        xb, slab, L, DCH, nullptr);
    conv_kernel<<<DCH, 256, 0, stream>>>(slab, Kf);
    transpose_kernel<<<dim3(L / 32, DCH / 32), dim3(32, 8), 0, stream>>>(
        slab, ob, DCH, L, bias);
  }
}

// Round 5
// 788.308 us; speedup vs baseline: 1.2032x; 1.0345x over previous
//
#include <hip/hip_runtime.h>
#include <math.h>

#define L     8192
#define DCH   768
#define BATCH 4
#define M     8192   // complex FFT size (real FFT size 16384 via packing)
#define MLOG  13
#define TPB   512    // threads per block for FFT kernels

// LDS bank swizzle: bijective, bounds all FFT-round patterns to <=4-way
#define PHYS(i) ((i) ^ (((i) >> 4) & 15))

__device__ __forceinline__ float2 cmul(float2 a, float2 b) {
  return make_float2(a.x * b.x - a.y * b.y, a.x * b.y + a.y * b.x);
}
__device__ __forceinline__ float2 cadd(float2 a, float2 b) {
  return make_float2(a.x + b.x, a.y + b.y);
}
__device__ __forceinline__ float2 csub(float2 a, float2 b) {
  return make_float2(a.x - b.x, a.y - b.y);
}
__device__ __forceinline__ float2 csq(float2 a) {
  return make_float2(a.x * a.x - a.y * a.y, 2.0f * a.x * a.y);
}
__device__ __forceinline__ float2 conj2(float2 a) { return make_float2(a.x, -a.y); }

__device__ __forceinline__ int brev13(int n) {
  return (int)(__brev((unsigned)n) >> 19);
}

__device__ __forceinline__ float2 twiddle(float ang) {  // exp(i*ang)
  float s, c;
  __sincosf(ang, &s, &c);
  return make_float2(c, s);
}

#define C8  0.70710678118654752f
#define C16 0.92387953251128676f
#define S16 0.38268343236508977f
__device__ const float2 W16C[8] = {
  {1.f, 0.f}, {C16, -S16}, {C8, -C8}, {S16, -C16},
  {0.f, -1.f}, {-S16, -C16}, {-C8, -C8}, {-C16, -S16}};
__device__ const float2 W8C[4] = {{1.f, 0.f}, {C8, -C8}, {0.f, -1.f}, {-C8, -C8}};

// ---- radix-8 DIF butterfly (3 stages, descending): twiddle on difference ----
__device__ __forceinline__ void r8_dif(float2 x[8], float2 w, float2 w2, float2 w4) {
  float2 y0 = cadd(x[0], x[4]), t0 = csub(x[0], x[4]);
  float2 y1 = cadd(x[1], x[5]), t1 = csub(x[1], x[5]);
  float2 y2 = cadd(x[2], x[6]), t2 = csub(x[2], x[6]);
  float2 y3 = cadd(x[3], x[7]), t3 = csub(x[3], x[7]);
  float2 y4 = cmul(t0, w);
  float2 y5 = cmul(t1, cmul(w, W8C[1]));
  float2 y6 = cmul(t2, cmul(w, W8C[2]));
  float2 y7 = cmul(t3, cmul(w, W8C[3]));
  float2 w2n = make_float2(w2.y, -w2.x);   // w2 * (-i)
  float2 z0 = cadd(y0, y2), z2 = cmul(csub(y0, y2), w2);
  float2 z1 = cadd(y1, y3), z3 = cmul(csub(y1, y3), w2n);
  float2 z4 = cadd(y4, y6), z6 = cmul(csub(y4, y6), w2);
  float2 z5 = cadd(y5, y7), z7 = cmul(csub(y5, y7), w2n);
  x[0] = cadd(z0, z1); x[1] = cmul(csub(z0, z1), w4);
  x[2] = cadd(z2, z3); x[3] = cmul(csub(z2, z3), w4);
  x[4] = cadd(z4, z5); x[5] = cmul(csub(z4, z5), w4);
  x[6] = cadd(z6, z7); x[7] = cmul(csub(z6, z7), w4);
}

// ---- radix-8 DIT butterfly (3 stages, ascending): twiddle before add ----
__device__ __forceinline__ void r8_dit(float2 x[8], float2 w, float2 w2, float2 w4) {
  float2 a1 = cmul(x[1], w4), a3 = cmul(x[3], w4);
  float2 a5 = cmul(x[5], w4), a7 = cmul(x[7], w4);
  float2 y0 = cadd(x[0], a1), y1 = csub(x[0], a1);
  float2 y2 = cadd(x[2], a3), y3 = csub(x[2], a3);
  float2 y4 = cadd(x[4], a5), y5 = csub(x[4], a5);
  float2 y6 = cadd(x[6], a7), y7 = csub(x[6], a7);
  float2 w2n = make_float2(w2.y, -w2.x);
  float2 b2 = cmul(y2, w2), b3 = cmul(y3, w2n);
  float2 b6 = cmul(y6, w2), b7 = cmul(y7, w2n);
  float2 z0 = cadd(y0, b2), z2 = csub(y0, b2);
  float2 z1 = cadd(y1, b3), z3 = csub(y1, b3);
  float2 z4 = cadd(y4, b6), z6 = csub(y4, b6);
  float2 z5 = cadd(y5, b7), z7 = csub(y5, b7);
  float2 c4 = cmul(z4, w);
  float2 c5 = cmul(z5, cmul(w, W8C[1]));
  float2 c6 = cmul(z6, cmul(w, W8C[2]));
  float2 c7 = cmul(z7, cmul(w, W8C[3]));
  x[0] = cadd(z0, c4); x[4] = csub(z0, c4);
  x[1] = cadd(z1, c5); x[5] = csub(z1, c5);
  x[2] = cadd(z2, c6); x[6] = csub(z2, c6);
  x[3] = cadd(z3, c7); x[7] = csub(z3, c7);
}

// ---- one LDS round of radix-8 groups (in-place, same-thread read/write) ----
template <int S, bool DIF>
__device__ __forceinline__ void r8_round(float2* A, int tid) {
  const int half = 1 << S;
  #pragma unroll
  for (int i = 0; i < (M / 8) / TPB; ++i) {
    int g = tid + i * TPB;
    int pos = g & (half - 1);
    int base = ((g >> S) << (S + 3)) | pos;
    float2 x[8];
    #pragma unroll
    for (int u = 0; u < 8; ++u) x[u] = A[PHYS(base + (u << S))];
    float2 w, w2, w4;
    if constexpr (S == 0) {
      w = make_float2(1.f, 0.f); w2 = w; w4 = w;
    } else {
      w = twiddle(-6.2831853071795864769f * (float)pos / (float)(8 << S));
      w2 = csq(w); w4 = csq(w2);
    }
    if constexpr (DIF) r8_dif(x, w, w2, w4); else r8_dit(x, w, w2, w4);
    #pragma unroll
    for (int u = 0; u < 8; ++u) A[PHYS(base + (u << S))] = x[u];
  }
}

// Forward DIF rounds over LDS: input = src (4096 nonzero float2, upper half zero)
// round1: radix-16 (stages 12..9) reading global directly, skipping zero half.
__device__ __forceinline__ void fwd_fft(float2* A, const float2* __restrict__ src,
                                        int tid) {
  {
    int pos = tid;                       // [0, 512)
    float2 x[8], hi[8];
    #pragma unroll
    for (int u = 0; u < 8; ++u) x[u] = src[pos + (u << 9)];
    float2 v = twiddle(-6.2831853071795864769f * (float)pos / 8192.0f);
    float2 v2 = csq(v), v4 = csq(v2), v8 = csq(v4);
    #pragma unroll
    for (int u = 0; u < 8; ++u) hi[u] = cmul(x[u], cmul(v, W16C[u]));
    r8_dif(x, v2, v4, v8);
    r8_dif(hi, v2, v4, v8);
    #pragma unroll
    for (int u = 0; u < 8; ++u) A[PHYS(pos + (u << 9))] = x[u];
    #pragma unroll
    for (int u = 0; u < 8; ++u) A[PHYS(pos + ((u + 8) << 9))] = hi[u];
  }
  __syncthreads();
  r8_round<6, true>(A, tid);
  __syncthreads();
  r8_round<3, true>(A, tid);
  __syncthreads();
  r8_round<0, true>(A, tid);
  __syncthreads();
}

// ---------------- Kernel 1: implicit-filter MLP -> S[L][64] ----------------
__global__ __launch_bounds__(256) void mlp_kernel(
    const float* __restrict__ w0, const float* __restrict__ b0,
    const float* __restrict__ w1, const float* __restrict__ b1,
    const float* __restrict__ freq, float* __restrict__ S) {
  __shared__ float w1s[64 * 64];
  __shared__ float w0s[3 * 64];
  __shared__ float b0s[64], b1s[64], fqs[64];
  int tid = threadIdx.x;
  for (int i = tid; i < 4096; i += 256) w1s[i] = w1[i];
  if (tid < 192) w0s[tid] = w0[tid];
  if (tid < 64) { b0s[tid] = b0[tid]; b1s[tid] = b1[tid]; fqs[tid] = freq[tid]; }
  __syncthreads();

  int n = blockIdx.x * 256 + tid;
  float t  = (float)n / (float)(L - 1);
  float th = 1e-4f * (6.2831853071795864769f * (float)n / (float)L);
  float z1 = cosf(th);
  float z2 = -sinf(th);

  float h0[64];
  #pragma unroll
  for (int j = 0; j < 64; ++j) {
    float a = t * w0s[j] + z1 * w0s[64 + j] + z2 * w0s[128 + j] + b0s[j];
    h0[j] = sinf(fqs[j] * a);
  }
  float* Srow = S + (size_t)n * 64;
  for (int j = 0; j < 64; ++j) {
    float acc = b1s[j];
    #pragma unroll
    for (int i = 0; i < 64; ++i) acc += h0[i] * w1s[i * 64 + j];
    Srow[j] = sinf(fqs[j] * acc);
  }
}

// ------- Kernel 2: k_t[d][n] = (S[n]·w2[:,d] + b2[d]) * exp(-t|delta_d|) -------
__global__ __launch_bounds__(256) void kfilter_kernel(
    const float* __restrict__ S, const float* __restrict__ w2,
    const float* __restrict__ b2, const float* __restrict__ deltas,
    float* __restrict__ kt) {
  __shared__ float Ss[64][65];
  int tid = threadIdx.x;
  int n0 = blockIdx.x * 64;
  int d0 = blockIdx.y * 4;
  #pragma unroll
  for (int i = 0; i < 16; ++i) {
    int idx = tid + i * 256;
    Ss[idx >> 6][idx & 63] = S[(size_t)n0 * 64 + idx];
  }
  __syncthreads();
  int nn = tid & 63, dd = tid >> 6;
  int d = d0 + dd, n = n0 + nn;
  float acc = b2[d];
  #pragma unroll 8
  for (int j = 0; j < 64; ++j) acc += Ss[nn][j] * w2[j * DCH + d];
  float t = (float)n / (float)(L - 1);
  float decay = expf(-t * fabsf(deltas[d]));
  kt[(size_t)d * L + n] = acc * decay;  // SHIFT = 0
}

// ---------------- tiled transpose src[R][C] -> dst[C][R] (+ optional bias[r]) ----------------
__global__ __launch_bounds__(256) void transpose_kernel(
    const float* __restrict__ src, float* __restrict__ dst,
    int R, int C, const float* __restrict__ bias) {
  __shared__ float tile[32][33];
  int c0 = blockIdx.x * 32, r0 = blockIdx.y * 32;
  int tx = threadIdx.x, ty = threadIdx.y;
  #pragma unroll
  for (int k = 0; k < 4; ++k) {
    int r = r0 + ty + k * 8;
    tile[ty + k * 8][tx] = src[(size_t)r * C + c0 + tx];
  }
  __syncthreads();
  float bv = (bias != nullptr) ? bias[r0 + tx] : 0.0f;
  #pragma unroll
  for (int k = 0; k < 4; ++k) {
    int c = c0 + ty + k * 8;
    dst[(size_t)c * R + r0 + tx] = tile[tx][ty + k * 8] + bv;
  }
}

// ---- Kernel 4: filter FFT -> Kf_br[d][p] = rfft(k_d,16384)[br13(p)]/16384 ----
// p=0 packs (R[0], R[8192]) (both real).
__global__ __launch_bounds__(TPB, 4) void fftk_kernel(
    const float* __restrict__ kt, float2* __restrict__ Kf) {
  __shared__ float2 A[M];
  int tid = threadIdx.x;
  int d = blockIdx.x;
  fwd_fft(A, (const float2*)(kt + (size_t)d * L), tid);

  float2* Kfd = Kf + (size_t)d * M;
  const float sc = 1.0f / 16384.0f;
  #pragma unroll 4
  for (int i = 0; i < M / TPB; ++i) {
    int p = tid + i * TPB;
    if (p == 0) {
      float2 Z0 = A[PHYS(0)];
      Kfd[0] = make_float2(sc * (Z0.x + Z0.y), sc * (Z0.x - Z0.y));
    } else {
      int t = 31 - __clz(p);
      int q = (3 << t) - 1 - p;         // partner position (same dyadic block)
      float2 Zk = A[PHYS(p)], Zj = A[PHYS(q)];
      float2 Ze = make_float2(0.5f * (Zk.x + Zj.x), 0.5f * (Zk.y - Zj.y));
      float2 Zo = make_float2(0.5f * (Zk.y + Zj.y), -0.5f * (Zk.x - Zj.x));
      int k = brev13(p);
      float2 W = twiddle(-3.14159265358979323846f * (float)k / 8192.0f);
      float2 U = cadd(Ze, cmul(W, Zo));  // R_filt[k]
      Kfd[p] = make_float2(sc * U.x, sc * U.y);
    }
  }
}

// ---------------- Kernel 5: per-channel FFT conv (in-place over one batch slab xt[D][L]) ----------------
// Pointwise phase is pair-owned: work item j handles positions {p, q} (disjoint
// across items) -> reads and writes confined to one thread, no barrier, no
// carry registers (round-3's outv[32] spilled to scratch: VGPR 256, +33MB WRITE).
__global__ __launch_bounds__(TPB, 4) void conv_kernel(
    float* __restrict__ xt, const float2* __restrict__ Kf) {
  __shared__ float2 A[M];
  int tid = threadIdx.x;
  int d = blockIdx.x;
  float2* ch = (float2*)(xt + (size_t)d * L);

  fwd_fft(A, ch, tid);

  const float2* Kfd = Kf + (size_t)d * M;
  #pragma unroll 2
  for (int i = 0; i < (M / 2) / TPB; ++i) {
    int j = tid + i * TPB;               // work item 0..4095
    if (j == 0) {
      // p = 0: packed (DC, Nyquist-of-16384), both real
      float2 Z0 = A[PHYS(0)];
      float U0 = Z0.x + Z0.y, UM = Z0.x - Z0.y;
      float2 C0 = Kfd[0];
      float V0 = U0 * C0.x, VM = UM * C0.y;
      A[PHYS(0)] = make_float2(0.5f * (V0 + VM), -0.5f * (V0 - VM));
      // p = 1: self-conjugate bin k = 4096 (W = -i); both pair formulas reduce to Y
      float2 Z1 = A[PHYS(1)];
      A[PHYS(1)] = cmul(conj2(Z1), Kfd[1]);
    } else {
      int hb = 1 << (31 - __clz(j));     // top bit of j
      int m = j - hb;
      int p = (hb << 1) + m;             // first half of dyadic block
      int q = (hb << 2) - 1 - m;         // Hermitian partner, second half
      float2 Zk = A[PHYS(p)], Zj = A[PHYS(q)];
      float2 Ze = make_float2(0.5f * (Zk.x + Zj.x), 0.5f * (Zk.y - Zj.y));
      float2 Zo = make_float2(0.5f * (Zk.y + Zj.y), -0.5f * (Zk.x - Zj.x));
      int k = brev13(p);
      float2 W = twiddle(-3.14159265358979323846f * (float)k / 8192.0f);
      float2 WZo = cmul(W, Zo);
      float2 Uk  = cadd(Ze, WZo);        // R_x[k]
      float2 Umc = csub(Ze, WZo);        // conj(R_x[M-k])
      float2 Ck = Kfd[p], Cj = Kfd[q];
      float2 Vk  = cmul(Uk, Ck);         // Y[k]
      float2 VjC = cmul(Umc, conj2(Cj)); // conj(Y[M-k])
      float2 Ye = make_float2(0.5f * (Vk.x + VjC.x), 0.5f * (Vk.y + VjC.y));
      float2 G  = make_float2(0.5f * (Vk.x - VjC.x), 0.5f * (Vk.y - VjC.y));
      float2 Yo = cmul(conj2(W), G);
      A[PHYS(p)] = make_float2(Ye.x - Yo.y, -(Ye.y + Yo.x));  // conj(Z'[k])
      A[PHYS(q)] = make_float2(Ye.x + Yo.y, Ye.y - Yo.x);     // conj(Z'[M-k])
    }
  }
  __syncthreads();

  // inverse via DIT on conj'd spectrum (bitrev layout is exactly DIT input)
  r8_round<0, false>(A, tid);
  __syncthreads();
  r8_round<3, false>(A, tid);
  __syncthreads();
  r8_round<6, false>(A, tid);
  __syncthreads();

  // final radix-16 DIT (stages 9..12); only u<8 outputs needed (n < 4096)
  const float inv = 1.0f / (float)M;
  {
    int pos = tid;
    float2 xl[8], xh[8];
    #pragma unroll
    for (int u = 0; u < 8; ++u) xl[u] = A[PHYS(pos + (u << 9))];
    #pragma unroll
    for (int u = 0; u < 8; ++u) xh[u] = A[PHYS(pos + ((u + 8) << 9))];
    float2 v = twiddle(-6.2831853071795864769f * (float)pos / 8192.0f);
    float2 v2 = csq(v), v4 = csq(v2), v8 = csq(v4);
    r8_dit(xl, v2, v4, v8);
    r8_dit(xh, v2, v4, v8);
    #pragma unroll
    for (int u = 0; u < 8; ++u) {
      float2 F = cadd(xl[u], cmul(cmul(v, W16C[u]), xh[u]));
      ch[pos + (u << 9)] = make_float2(F.x * inv, -F.y * inv);
    }
  }
}

extern "C" void kernel_launch(void* const* d_in, const int* in_sizes, int n_in,
                              void* d_out, int out_size, void* d_ws, size_t ws_size,
                              hipStream_t stream) {
  const float* x      = (const float*)d_in[0];
  const float* w0     = (const float*)d_in[1];
  const float* b0     = (const float*)d_in[2];
  const float* w1     = (const float*)d_in[3];
  const float* b1     = (const float*)d_in[4];
  const float* w2     = (const float*)d_in[5];
  const float* b2     = (const float*)d_in[6];
  const float* freq   = (const float*)d_in[7];
  const float* deltas = (const float*)d_in[8];
  const float* bias   = (const float*)d_in[9];
  float* out = (float*)d_out;

  // workspace layout (74 MB): [S: 2 MB][Kf: 48 MB][slab: 24 MB]
  // slab = kt until fftk consumes it, then per-batch transposed-x buffer.
  float*  S    = (float*)d_ws;
  float2* Kf   = (float2*)(S + (size_t)L * 64);
  float*  slab = (float*)(Kf + (size_t)DCH * M);

  mlp_kernel<<<32, 256, 0, stream>>>(w0, b0, w1, b1, freq, S);
  kfilter_kernel<<<dim3(128, 192), 256, 0, stream>>>(S, w2, b2, deltas, slab);
  fftk_kernel<<<DCH, TPB, 0, stream>>>(slab, Kf);

  for (int b = 0; b < BATCH; ++b) {
    const float* xb = x + (size_t)b * L * DCH;
    float* ob = out + (size_t)b * L * DCH;
    transpose_kernel<<<dim3(DCH / 32, L / 32), dim3(32, 8), 0, stream>>>(
        xb, slab, L, DCH, nullptr);
    conv_kernel<<<DCH, TPB, 0, stream>>>(slab, Kf);
    transpose_kernel<<<dim3(L / 32, DCH / 32), dim3(32, 8), 0, stream>>>(
        slab, ob, DCH, L, bias);
  }
}

// Round 9
// 543.170 us; speedup vs baseline: 1.7463x; 1.4513x over previous
//
#include <hip/hip_runtime.h>
#include <math.h>

#define L     8192
#define DCH   768
#define BATCH 4
#define M     8192   // complex FFT size (real FFT size 16384 via packing)
#define MLOG  13
#define TPB   512    // threads per block for FFT kernels

// LDS bank swizzle: bijective, bounds all FFT-round patterns to <=4-way
#define PHYS(i) ((i) ^ (((i) >> 4) & 15))

__device__ __forceinline__ float2 cmul(float2 a, float2 b) {
  return make_float2(a.x * b.x - a.y * b.y, a.x * b.y + a.y * b.x);
}
__device__ __forceinline__ float2 cadd(float2 a, float2 b) {
  return make_float2(a.x + b.x, a.y + b.y);
}
__device__ __forceinline__ float2 csub(float2 a, float2 b) {
  return make_float2(a.x - b.x, a.y - b.y);
}
__device__ __forceinline__ float2 csq(float2 a) {
  return make_float2(a.x * a.x - a.y * a.y, 2.0f * a.x * a.y);
}
__device__ __forceinline__ float2 conj2(float2 a) { return make_float2(a.x, -a.y); }

__device__ __forceinline__ int brev13(int n) {
  return (int)(__brev((unsigned)n) >> 19);
}

__device__ __forceinline__ float2 twiddle(float ang) {  // exp(i*ang)
  float s, c;
  __sincosf(ang, &s, &c);
  return make_float2(c, s);
}

#define C8  0.70710678118654752f
#define C16 0.92387953251128676f
#define S16 0.38268343236508977f
__device__ const float2 W16C[8] = {
  {1.f, 0.f}, {C16, -S16}, {C8, -C8}, {S16, -C16},
  {0.f, -1.f}, {-S16, -C16}, {-C8, -C8}, {-C16, -S16}};
__device__ const float2 W8C[4] = {{1.f, 0.f}, {C8, -C8}, {0.f, -1.f}, {-C8, -C8}};

// ---- radix-8 DIF butterfly (3 stages, descending): twiddle on difference ----
__device__ __forceinline__ void r8_dif(float2 x[8], float2 w, float2 w2, float2 w4) {
  float2 y0 = cadd(x[0], x[4]), t0 = csub(x[0], x[4]);
  float2 y1 = cadd(x[1], x[5]), t1 = csub(x[1], x[5]);
  float2 y2 = cadd(x[2], x[6]), t2 = csub(x[2], x[6]);
  float2 y3 = cadd(x[3], x[7]), t3 = csub(x[3], x[7]);
  float2 y4 = cmul(t0, w);
  float2 y5 = cmul(t1, cmul(w, W8C[1]));
  float2 y6 = cmul(t2, cmul(w, W8C[2]));
  float2 y7 = cmul(t3, cmul(w, W8C[3]));
  float2 w2n = make_float2(w2.y, -w2.x);   // w2 * (-i)
  float2 z0 = cadd(y0, y2), z2 = cmul(csub(y0, y2), w2);
  float2 z1 = cadd(y1, y3), z3 = cmul(csub(y1, y3), w2n);
  float2 z4 = cadd(y4, y6), z6 = cmul(csub(y4, y6), w2);
  float2 z5 = cadd(y5, y7), z7 = cmul(csub(y5, y7), w2n);
  x[0] = cadd(z0, z1); x[1] = cmul(csub(z0, z1), w4);
  x[2] = cadd(z2, z3); x[3] = cmul(csub(z2, z3), w4);
  x[4] = cadd(z4, z5); x[5] = cmul(csub(z4, z5), w4);
  x[6] = cadd(z6, z7); x[7] = cmul(csub(z6, z7), w4);
}

// ---- radix-8 DIT butterfly (3 stages, ascending): twiddle before add ----
__device__ __forceinline__ void r8_dit(float2 x[8], float2 w, float2 w2, float2 w4) {
  float2 a1 = cmul(x[1], w4), a3 = cmul(x[3], w4);
  float2 a5 = cmul(x[5], w4), a7 = cmul(x[7], w4);
  float2 y0 = cadd(x[0], a1), y1 = csub(x[0], a1);
  float2 y2 = cadd(x[2], a3), y3 = csub(x[2], a3);
  float2 y4 = cadd(x[4], a5), y5 = csub(x[4], a5);
  float2 y6 = cadd(x[6], a7), y7 = csub(x[6], a7);
  float2 w2n = make_float2(w2.y, -w2.x);
  float2 b2 = cmul(y2, w2), b3 = cmul(y3, w2n);
  float2 b6 = cmul(y6, w2), b7 = cmul(y7, w2n);
  float2 z0 = cadd(y0, b2), z2 = csub(y0, b2);
  float2 z1 = cadd(y1, b3), z3 = csub(y1, b3);
  float2 z4 = cadd(y4, b6), z6 = csub(y4, b6);
  float2 z5 = cadd(y5, b7), z7 = csub(y5, b7);
  float2 c4 = cmul(z4, w);
  float2 c5 = cmul(z5, cmul(w, W8C[1]));
  float2 c6 = cmul(z6, cmul(w, W8C[2]));
  float2 c7 = cmul(z7, cmul(w, W8C[3]));
  x[0] = cadd(z0, c4); x[4] = csub(z0, c4);
  x[1] = cadd(z1, c5); x[5] = csub(z1, c5);
  x[2] = cadd(z2, c6); x[6] = csub(z2, c6);
  x[3] = cadd(z3, c7); x[7] = csub(z3, c7);
}

// ---- one LDS round of radix-8 groups (in-place, same-thread read/write) ----
template <int S, bool DIF>
__device__ __forceinline__ void r8_round(float2* A, int tid) {
  const int half = 1 << S;
  #pragma unroll
  for (int i = 0; i < (M / 8) / TPB; ++i) {
    int g = tid + i * TPB;
    int pos = g & (half - 1);
    int base = ((g >> S) << (S + 3)) | pos;
    float2 x[8];
    #pragma unroll
    for (int u = 0; u < 8; ++u) x[u] = A[PHYS(base + (u << S))];
    float2 w, w2, w4;
    if constexpr (S == 0) {
      w = make_float2(1.f, 0.f); w2 = w; w4 = w;
    } else {
      w = twiddle(-6.2831853071795864769f * (float)pos / (float)(8 << S));
      w2 = csq(w); w4 = csq(w2);
    }
    if constexpr (DIF) r8_dif(x, w, w2, w4); else r8_dit(x, w, w2, w4);
    #pragma unroll
    for (int u = 0; u < 8; ++u) A[PHYS(base + (u << S))] = x[u];
  }
}

// Forward DIF rounds over LDS: input = src (4096 nonzero float2, upper half zero)
// round1: radix-16 (stages 12..9) reading global directly, skipping zero half.
__device__ __forceinline__ void fwd_fft(float2* A, const float2* __restrict__ src,
                                        int tid) {
  {
    int pos = tid;                       // [0, 512)
    float2 x[8], hi[8];
    #pragma unroll
    for (int u = 0; u < 8; ++u) x[u] = src[pos + (u << 9)];
    float2 v = twiddle(-6.2831853071795864769f * (float)pos / 8192.0f);
    float2 v2 = csq(v), v4 = csq(v2), v8 = csq(v4);
    #pragma unroll
    for (int u = 0; u < 8; ++u) hi[u] = cmul(x[u], cmul(v, W16C[u]));
    r8_dif(x, v2, v4, v8);
    r8_dif(hi, v2, v4, v8);
    #pragma unroll
    for (int u = 0; u < 8; ++u) A[PHYS(pos + (u << 9))] = x[u];
    #pragma unroll
    for (int u = 0; u < 8; ++u) A[PHYS(pos + ((u + 8) << 9))] = hi[u];
  }
  __syncthreads();
  r8_round<6, true>(A, tid);
  __syncthreads();
  r8_round<3, true>(A, tid);
  __syncthreads();
  r8_round<0, true>(A, tid);
  __syncthreads();
}

// ---------------- Kernel 1: implicit-filter MLP -> S[L][64] ----------------
__global__ __launch_bounds__(256) void mlp_kernel(
    const float* __restrict__ w0, const float* __restrict__ b0,
    const float* __restrict__ w1, const float* __restrict__ b1,
    const float* __restrict__ freq, float* __restrict__ S) {
  __shared__ float w1s[64 * 64];
  __shared__ float w0s[3 * 64];
  __shared__ float b0s[64], b1s[64], fqs[64];
  int tid = threadIdx.x;
  for (int i = tid; i < 4096; i += 256) w1s[i] = w1[i];
  if (tid < 192) w0s[tid] = w0[tid];
  if (tid < 64) { b0s[tid] = b0[tid]; b1s[tid] = b1[tid]; fqs[tid] = freq[tid]; }
  __syncthreads();

  int n = blockIdx.x * 256 + tid;
  float t  = (float)n / (float)(L - 1);
  float th = 1e-4f * (6.2831853071795864769f * (float)n / (float)L);
  float z1 = cosf(th);
  float z2 = -sinf(th);

  float h0[64];
  #pragma unroll
  for (int j = 0; j < 64; ++j) {
    float a = t * w0s[j] + z1 * w0s[64 + j] + z2 * w0s[128 + j] + b0s[j];
    h0[j] = sinf(fqs[j] * a);
  }
  float* Srow = S + (size_t)n * 64;
  for (int j = 0; j < 64; ++j) {
    float acc = b1s[j];
    #pragma unroll
    for (int i = 0; i < 64; ++i) acc += h0[i] * w1s[i * 64 + j];
    Srow[j] = sinf(fqs[j] * acc);
  }
}

// ------- Kernel 2: k_t[d][n] = (S[n]·w2[:,d] + b2[d]) * exp(-t|delta_d|) -------
__global__ __launch_bounds__(256) void kfilter_kernel(
    const float* __restrict__ S, const float* __restrict__ w2,
    const float* __restrict__ b2, const float* __restrict__ deltas,
    float* __restrict__ kt) {
  __shared__ float Ss[64][65];
  int tid = threadIdx.x;
  int n0 = blockIdx.x * 64;
  int d0 = blockIdx.y * 4;
  #pragma unroll
  for (int i = 0; i < 16; ++i) {
    int idx = tid + i * 256;
    Ss[idx >> 6][idx & 63] = S[(size_t)n0 * 64 + idx];
  }
  __syncthreads();
  int nn = tid & 63, dd = tid >> 6;
  int d = d0 + dd, n = n0 + nn;
  float acc = b2[d];
  #pragma unroll 8
  for (int j = 0; j < 64; ++j) acc += Ss[nn][j] * w2[j * DCH + d];
  float t = (float)n / (float)(L - 1);
  float decay = expf(-t * fabsf(deltas[d]));
  kt[(size_t)d * L + n] = acc * decay;  // SHIFT = 0
}

// ---------------- tiled transpose src[R][C] -> dst[C][R] (+ optional bias[r]) ----------------
__global__ __launch_bounds__(256) void transpose_kernel(
    const float* __restrict__ src, float* __restrict__ dst,
    int R, int C, const float* __restrict__ bias) {
  __shared__ float tile[32][33];
  int c0 = blockIdx.x * 32, r0 = blockIdx.y * 32;
  int tx = threadIdx.x, ty = threadIdx.y;
  #pragma unroll
  for (int k = 0; k < 4; ++k) {
    int r = r0 + ty + k * 8;
    tile[ty + k * 8][tx] = src[(size_t)r * C + c0 + tx];
  }
  __syncthreads();
  float bv = (bias != nullptr) ? bias[r0 + tx] : 0.0f;
  #pragma unroll
  for (int k = 0; k < 4; ++k) {
    int c = c0 + ty + k * 8;
    dst[(size_t)c * R + r0 + tx] = tile[tx][ty + k * 8] + bv;
  }
}

// ---- Kernel 4: filter FFT -> Kf_br[d][p] = rfft(k_d,16384)[br13(p)]/16384 ----
// p=0 packs (R[0], R[8192]) (both real).
__global__ __launch_bounds__(TPB, 2) void fftk_kernel(
    const float* __restrict__ kt, float2* __restrict__ Kf) {
  __shared__ float2 A[M];
  int tid = threadIdx.x;
  int d = blockIdx.x;
  fwd_fft(A, (const float2*)(kt + (size_t)d * L), tid);

  float2* Kfd = Kf + (size_t)d * M;
  const float sc = 1.0f / 16384.0f;
  #pragma unroll 4
  for (int i = 0; i < M / TPB; ++i) {
    int p = tid + i * TPB;
    if (p == 0) {
      float2 Z0 = A[PHYS(0)];
      Kfd[0] = make_float2(sc * (Z0.x + Z0.y), sc * (Z0.x - Z0.y));
    } else {
      int t = 31 - __clz(p);
      int q = (3 << t) - 1 - p;         // partner position (same dyadic block)
      float2 Zk = A[PHYS(p)], Zj = A[PHYS(q)];
      float2 Ze = make_float2(0.5f * (Zk.x + Zj.x), 0.5f * (Zk.y - Zj.y));
      float2 Zo = make_float2(0.5f * (Zk.y + Zj.y), -0.5f * (Zk.x - Zj.x));
      int k = brev13(p);
      float2 W = twiddle(-3.14159265358979323846f * (float)k / 8192.0f);
      float2 U = cadd(Ze, cmul(W, Zo));  // R_filt[k]
      Kfd[p] = make_float2(sc * U.x, sc * U.y);
    }
  }
}

// ---------------- Kernel 5: per-channel FFT conv (in-place over one batch slab xt[D][L]) ----------------
// Pointwise phase is pair-owned: work item j handles positions {p, q} (disjoint
// across items) -> reads and writes confined to one thread, no barrier, no
// carry registers. Launch bound (TPB,2): round-5's (TPB,4) capped VGPR at 64
// -> 183MB/dispatch scratch-spill writes, conv memory-bound at 45% HBM.
__global__ __launch_bounds__(TPB, 2) void conv_kernel(
    float* __restrict__ xt, const float2* __restrict__ Kf) {
  __shared__ float2 A[M];
  int tid = threadIdx.x;
  int d = blockIdx.x;
  float2* ch = (float2*)(xt + (size_t)d * L);

  fwd_fft(A, ch, tid);

  const float2* Kfd = Kf + (size_t)d * M;
  #pragma unroll 2
  for (int i = 0; i < (M / 2) / TPB; ++i) {
    int j = tid + i * TPB;               // work item 0..4095
    if (j == 0) {
      // p = 0: packed (DC, Nyquist-of-16384), both real
      float2 Z0 = A[PHYS(0)];
      float U0 = Z0.x + Z0.y, UM = Z0.x - Z0.y;
      float2 C0 = Kfd[0];
      float V0 = U0 * C0.x, VM = UM * C0.y;
      A[PHYS(0)] = make_float2(0.5f * (V0 + VM), -0.5f * (V0 - VM));
      // p = 1: self-conjugate bin k = 4096 (W = -i); both pair formulas reduce to Y
      float2 Z1 = A[PHYS(1)];
      A[PHYS(1)] = cmul(conj2(Z1), Kfd[1]);
    } else {
      int hb = 1 << (31 - __clz(j));     // top bit of j
      int m = j - hb;
      int p = (hb << 1) + m;             // first half of dyadic block
      int q = (hb << 2) - 1 - m;         // Hermitian partner, second half
      float2 Zk = A[PHYS(p)], Zj = A[PHYS(q)];
      float2 Ze = make_float2(0.5f * (Zk.x + Zj.x), 0.5f * (Zk.y - Zj.y));
      float2 Zo = make_float2(0.5f * (Zk.y + Zj.y), -0.5f * (Zk.x - Zj.x));
      int k = brev13(p);
      float2 W = twiddle(-3.14159265358979323846f * (float)k / 8192.0f);
      float2 WZo = cmul(W, Zo);
      float2 Uk  = cadd(Ze, WZo);        // R_x[k]
      float2 Umc = csub(Ze, WZo);        // conj(R_x[M-k])
      float2 Ck = Kfd[p], Cj = Kfd[q];
      float2 Vk  = cmul(Uk, Ck);         // Y[k]
      float2 VjC = cmul(Umc, conj2(Cj)); // conj(Y[M-k])
      float2 Ye = make_float2(0.5f * (Vk.x + VjC.x), 0.5f * (Vk.y + VjC.y));
      float2 G  = make_float2(0.5f * (Vk.x - VjC.x), 0.5f * (Vk.y - VjC.y));
      float2 Yo = cmul(conj2(W), G);
      A[PHYS(p)] = make_float2(Ye.x - Yo.y, -(Ye.y + Yo.x));  // conj(Z'[k])
      A[PHYS(q)] = make_float2(Ye.x + Yo.y, Ye.y - Yo.x);     // conj(Z'[M-k])
    }
  }
  __syncthreads();

  // inverse via DIT on conj'd spectrum (bitrev layout is exactly DIT input)
  r8_round<0, false>(A, tid);
  __syncthreads();
  r8_round<3, false>(A, tid);
  __syncthreads();
  r8_round<6, false>(A, tid);
  __syncthreads();

  // final radix-16 DIT (stages 9..12); only u<8 outputs needed (n < 4096)
  const float inv = 1.0f / (float)M;
  {
    int pos = tid;
    float2 xl[8], xh[8];
    #pragma unroll
    for (int u = 0; u < 8; ++u) xl[u] = A[PHYS(pos + (u << 9))];
    #pragma unroll
    for (int u = 0; u < 8; ++u) xh[u] = A[PHYS(pos + ((u + 8) << 9))];
    float2 v = twiddle(-6.2831853071795864769f * (float)pos / 8192.0f);
    float2 v2 = csq(v), v4 = csq(v2), v8 = csq(v4);
    r8_dit(xl, v2, v4, v8);
    r8_dit(xh, v2, v4, v8);
    #pragma unroll
    for (int u = 0; u < 8; ++u) {
      float2 F = cadd(xl[u], cmul(cmul(v, W16C[u]), xh[u]));
      ch[pos + (u << 9)] = make_float2(F.x * inv, -F.y * inv);
    }
  }
}

extern "C" void kernel_launch(void* const* d_in, const int* in_sizes, int n_in,
                              void* d_out, int out_size, void* d_ws, size_t ws_size,
                              hipStream_t stream) {
  const float* x      = (const float*)d_in[0];
  const float* w0     = (const float*)d_in[1];
  const float* b0     = (const float*)d_in[2];
  const float* w1     = (const float*)d_in[3];
  const float* b1     = (const float*)d_in[4];
  const float* w2     = (const float*)d_in[5];
  const float* b2     = (const float*)d_in[6];
  const float* freq   = (const float*)d_in[7];
  const float* deltas = (const float*)d_in[8];
  const float* bias   = (const float*)d_in[9];
  float* out = (float*)d_out;

  // workspace layout (74 MB): [S: 2 MB][Kf: 48 MB][slab: 24 MB]
  // slab = kt until fftk consumes it, then per-batch transposed-x buffer.
  float*  S    = (float*)d_ws;
  float2* Kf   = (float2*)(S + (size_t)L * 64);
  float*  slab = (float*)(Kf + (size_t)DCH * M);

  mlp_kernel<<<32, 256, 0, stream>>>(w0, b0, w1, b1, freq, S);
  kfilter_kernel<<<dim3(128, 192), 256, 0, stream>>>(S, w2, b2, deltas, slab);
  fftk_kernel<<<DCH, TPB, 0, stream>>>(slab, Kf);

  for (int b = 0; b < BATCH; ++b) {
    const float* xb = x + (size_t)b * L * DCH;
    float* ob = out + (size_t)b * L * DCH;
    transpose_kernel<<<dim3(DCH / 32, L / 32), dim3(32, 8), 0, stream>>>(
        xb, slab, L, DCH, nullptr);
    conv_kernel<<<DCH, TPB, 0, stream>>>(slab, Kf);
    transpose_kernel<<<dim3(L / 32, DCH / 32), dim3(32, 8), 0, stream>>>(
        slab, ob, DCH, L, bias);
  }
}

// Round 11
// 487.907 us; speedup vs baseline: 1.9440x; 1.1133x over previous
//
#include <hip/hip_runtime.h>
#include <math.h>

#define L     8192
#define DCH   768
#define BATCH 4
#define M     8192   // complex FFT size (real FFT size 16384 via packing)
#define MLOG  13
#define TPB   512    // threads per block for FFT kernels

// LDS bank swizzle: bijective, bounds all FFT-round patterns to <=4-way
#define PHYS(i) ((i) ^ (((i) >> 4) & 15))

__device__ __forceinline__ float2 cmul(float2 a, float2 b) {
  return make_float2(a.x * b.x - a.y * b.y, a.x * b.y + a.y * b.x);
}
__device__ __forceinline__ float2 cadd(float2 a, float2 b) {
  return make_float2(a.x + b.x, a.y + b.y);
}
__device__ __forceinline__ float2 csub(float2 a, float2 b) {
  return make_float2(a.x - b.x, a.y - b.y);
}
__device__ __forceinline__ float2 csq(float2 a) {
  return make_float2(a.x * a.x - a.y * a.y, 2.0f * a.x * a.y);
}
__device__ __forceinline__ float2 conj2(float2 a) { return make_float2(a.x, -a.y); }

__device__ __forceinline__ int brev13(int n) {
  return (int)(__brev((unsigned)n) >> 19);
}

__device__ __forceinline__ float2 twiddle(float ang) {  // exp(i*ang)
  float s, c;
  __sincosf(ang, &s, &c);
  return make_float2(c, s);
}

#define C8  0.70710678118654752f
#define C16 0.92387953251128676f
#define S16 0.38268343236508977f
__device__ const float2 W16C[8] = {
  {1.f, 0.f}, {C16, -S16}, {C8, -C8}, {S16, -C16},
  {0.f, -1.f}, {-S16, -C16}, {-C8, -C8}, {-C16, -S16}};
__device__ const float2 W8C[4] = {{1.f, 0.f}, {C8, -C8}, {0.f, -1.f}, {-C8, -C8}};

// ---- radix-8 DIF butterfly (3 stages, descending): twiddle on difference ----
__device__ __forceinline__ void r8_dif(float2 x[8], float2 w, float2 w2, float2 w4) {
  float2 y0 = cadd(x[0], x[4]), t0 = csub(x[0], x[4]);
  float2 y1 = cadd(x[1], x[5]), t1 = csub(x[1], x[5]);
  float2 y2 = cadd(x[2], x[6]), t2 = csub(x[2], x[6]);
  float2 y3 = cadd(x[3], x[7]), t3 = csub(x[3], x[7]);
  float2 y4 = cmul(t0, w);
  float2 y5 = cmul(t1, cmul(w, W8C[1]));
  float2 y6 = cmul(t2, cmul(w, W8C[2]));
  float2 y7 = cmul(t3, cmul(w, W8C[3]));
  float2 w2n = make_float2(w2.y, -w2.x);   // w2 * (-i)
  float2 z0 = cadd(y0, y2), z2 = cmul(csub(y0, y2), w2);
  float2 z1 = cadd(y1, y3), z3 = cmul(csub(y1, y3), w2n);
  float2 z4 = cadd(y4, y6), z6 = cmul(csub(y4, y6), w2);
  float2 z5 = cadd(y5, y7), z7 = cmul(csub(y5, y7), w2n);
  x[0] = cadd(z0, z1); x[1] = cmul(csub(z0, z1), w4);
  x[2] = cadd(z2, z3); x[3] = cmul(csub(z2, z3), w4);
  x[4] = cadd(z4, z5); x[5] = cmul(csub(z4, z5), w4);
  x[6] = cadd(z6, z7); x[7] = cmul(csub(z6, z7), w4);
}

// ---- radix-8 DIT butterfly (3 stages, ascending): twiddle before add ----
__device__ __forceinline__ void r8_dit(float2 x[8], float2 w, float2 w2, float2 w4) {
  float2 a1 = cmul(x[1], w4), a3 = cmul(x[3], w4);
  float2 a5 = cmul(x[5], w4), a7 = cmul(x[7], w4);
  float2 y0 = cadd(x[0], a1), y1 = csub(x[0], a1);
  float2 y2 = cadd(x[2], a3), y3 = csub(x[2], a3);
  float2 y4 = cadd(x[4], a5), y5 = csub(x[4], a5);
  float2 y6 = cadd(x[6], a7), y7 = csub(x[6], a7);
  float2 w2n = make_float2(w2.y, -w2.x);
  float2 b2 = cmul(y2, w2), b3 = cmul(y3, w2n);
  float2 b6 = cmul(y6, w2), b7 = cmul(y7, w2n);
  float2 z0 = cadd(y0, b2), z2 = csub(y0, b2);
  float2 z1 = cadd(y1, b3), z3 = csub(y1, b3);
  float2 z4 = cadd(y4, b6), z6 = csub(y4, b6);
  float2 z5 = cadd(y5, b7), z7 = csub(y5, b7);
  float2 c4 = cmul(z4, w);
  float2 c5 = cmul(z5, cmul(w, W8C[1]));
  float2 c6 = cmul(z6, cmul(w, W8C[2]));
  float2 c7 = cmul(z7, cmul(w, W8C[3]));
  x[0] = cadd(z0, c4); x[4] = csub(z0, c4);
  x[1] = cadd(z1, c5); x[5] = csub(z1, c5);
  x[2] = cadd(z2, c6); x[6] = csub(z2, c6);
  x[3] = cadd(z3, c7); x[7] = csub(z3, c7);
}

// ---- one LDS round of radix-8 groups (in-place, same-thread read/write) ----
template <int S, bool DIF>
__device__ __forceinline__ void r8_round(float2* A, int tid) {
  const int half = 1 << S;
  #pragma unroll
  for (int i = 0; i < (M / 8) / TPB; ++i) {
    int g = tid + i * TPB;
    int pos = g & (half - 1);
    int base = ((g >> S) << (S + 3)) | pos;
    float2 x[8];
    #pragma unroll
    for (int u = 0; u < 8; ++u) x[u] = A[PHYS(base + (u << S))];
    float2 w, w2, w4;
    if constexpr (S == 0) {
      w = make_float2(1.f, 0.f); w2 = w; w4 = w;
    } else {
      w = twiddle(-6.2831853071795864769f * (float)pos / (float)(8 << S));
      w2 = csq(w); w4 = csq(w2);
    }
    if constexpr (DIF) r8_dif(x, w, w2, w4); else r8_dit(x, w, w2, w4);
    #pragma unroll
    for (int u = 0; u < 8; ++u) A[PHYS(base + (u << S))] = x[u];
  }
}

// Forward DIF rounds over LDS: input = src (4096 nonzero float2, upper half zero)
// round1: radix-16 (stages 12..9) reading global directly, skipping zero half.
__device__ __forceinline__ void fwd_fft(float2* A, const float2* __restrict__ src,
                                        int tid) {
  {
    int pos = tid;                       // [0, 512)
    float2 x[8], hi[8];
    #pragma unroll
    for (int u = 0; u < 8; ++u) x[u] = src[pos + (u << 9)];
    float2 v = twiddle(-6.2831853071795864769f * (float)pos / 8192.0f);
    float2 v2 = csq(v), v4 = csq(v2), v8 = csq(v4);
    #pragma unroll
    for (int u = 0; u < 8; ++u) hi[u] = cmul(x[u], cmul(v, W16C[u]));
    r8_dif(x, v2, v4, v8);
    r8_dif(hi, v2, v4, v8);
    #pragma unroll
    for (int u = 0; u < 8; ++u) A[PHYS(pos + (u << 9))] = x[u];
    #pragma unroll
    for (int u = 0; u < 8; ++u) A[PHYS(pos + ((u + 8) << 9))] = hi[u];
  }
  __syncthreads();
  r8_round<6, true>(A, tid);
  __syncthreads();
  r8_round<3, true>(A, tid);
  __syncthreads();
  r8_round<0, true>(A, tid);
  __syncthreads();
}

// ---------------- Kernel 1: implicit-filter MLP -> S[L][64] ----------------
// Restructured (was 32 blocks, 224 CUs idle): 128 blocks x 64 rows, h0 staged
// in LDS, phase-2 register-blocked 16 rows/thread with coalesced writes.
__global__ __launch_bounds__(256) void mlp_kernel(
    const float* __restrict__ w0, const float* __restrict__ b0,
    const float* __restrict__ w1, const float* __restrict__ b1,
    const float* __restrict__ freq, float* __restrict__ S) {
  __shared__ float w1s[64][65];
  __shared__ float h0s[64][65];
  __shared__ float w0s[3 * 64];
  __shared__ float b0s[64], b1s[64], fqs[64];
  int tid = threadIdx.x;
  #pragma unroll
  for (int i = 0; i < 16; ++i) {
    int idx = tid + i * 256;
    w1s[idx >> 6][idx & 63] = w1[idx];
  }
  if (tid < 192) w0s[tid] = w0[tid];
  if (tid < 64) { b0s[tid] = b0[tid]; b1s[tid] = b1[tid]; fqs[tid] = freq[tid]; }
  __syncthreads();

  int n0 = blockIdx.x * 64;
  {  // phase 1: h0 for this block's 64 rows; thread = (row, j-quarter)
    int r = tid & 63, qq = tid >> 6;
    int n = n0 + r;
    float t  = (float)n / (float)(L - 1);
    float th = 1e-4f * (6.2831853071795864769f * (float)n / (float)L);
    float sn, cs;
    __sincosf(th, &sn, &cs);
    float z1 = cs, z2 = -sn;
    #pragma unroll
    for (int jj = 0; jj < 16; ++jj) {
      int j = qq * 16 + jj;
      float a = t * w0s[j] + z1 * w0s[64 + j] + z2 * w0s[128 + j] + b0s[j];
      h0s[r][j] = sinf(fqs[j] * a);
    }
  }
  __syncthreads();
  {  // phase 2: thread = (col j, row-quarter); 16 rows register-blocked
    int j = tid & 63, rq = tid >> 6;
    float acc[16];
    #pragma unroll
    for (int r = 0; r < 16; ++r) acc[r] = b1s[j];
    for (int i = 0; i < 64; ++i) {
      float w = w1s[i][j];
      #pragma unroll
      for (int r = 0; r < 16; ++r) acc[r] += h0s[rq * 16 + r][i] * w;
    }
    float fq = fqs[j];
    #pragma unroll
    for (int r = 0; r < 16; ++r)
      S[(size_t)(n0 + rq * 16 + r) * 64 + j] = sinf(fq * acc[r]);
  }
}

// ------- Kernel 2: k_t[d][n] = (S[n]·w2[:,d] + b2[d]) * exp(-t|delta_d|) -------
// Register-blocked 4 outputs/thread along d (was 1 output, 8 inst/output,
// 83us VALU-bound): w2 row tile read as one broadcast float4 per j.
__global__ __launch_bounds__(256) void kfilter_kernel(
    const float* __restrict__ S, const float* __restrict__ w2,
    const float* __restrict__ b2, const float* __restrict__ deltas,
    float* __restrict__ kt) {
  __shared__ float Ss[64][65];
  int tid = threadIdx.x;
  int n0 = blockIdx.x * 64;
  int d0 = blockIdx.y * 16;
  #pragma unroll
  for (int i = 0; i < 16; ++i) {
    int idx = tid + i * 256;
    Ss[idx >> 6][idx & 63] = S[(size_t)n0 * 64 + idx];
  }
  __syncthreads();
  int nn = tid & 63;
  int d = d0 + (tid >> 6) * 4;   // each thread: outputs d..d+3
  int n = n0 + nn;
  float4 bv = *reinterpret_cast<const float4*>(b2 + d);
  float4 acc = bv;
  const float* w2p = w2 + d;
  #pragma unroll 8
  for (int j = 0; j < 64; ++j) {
    float s = Ss[nn][j];
    float4 w = *reinterpret_cast<const float4*>(w2p + (size_t)j * DCH);
    acc.x += s * w.x; acc.y += s * w.y; acc.z += s * w.z; acc.w += s * w.w;
  }
  float t = (float)n / (float)(L - 1);
  float4 dl = *reinterpret_cast<const float4*>(deltas + d);
  kt[(size_t)(d + 0) * L + n] = acc.x * expf(-t * fabsf(dl.x));
  kt[(size_t)(d + 1) * L + n] = acc.y * expf(-t * fabsf(dl.y));
  kt[(size_t)(d + 2) * L + n] = acc.z * expf(-t * fabsf(dl.z));
  kt[(size_t)(d + 3) * L + n] = acc.w * expf(-t * fabsf(dl.w));
}

// ---------------- tiled transpose src[R][C] -> dst[C][R] (+ optional bias[r]) ----------------
__global__ __launch_bounds__(256) void transpose_kernel(
    const float* __restrict__ src, float* __restrict__ dst,
    int R, int C, const float* __restrict__ bias) {
  __shared__ float tile[32][33];
  int c0 = blockIdx.x * 32, r0 = blockIdx.y * 32;
  int tx = threadIdx.x, ty = threadIdx.y;
  #pragma unroll
  for (int k = 0; k < 4; ++k) {
    int r = r0 + ty + k * 8;
    tile[ty + k * 8][tx] = src[(size_t)r * C + c0 + tx];
  }
  __syncthreads();
  float bv = (bias != nullptr) ? bias[r0 + tx] : 0.0f;
  #pragma unroll
  for (int k = 0; k < 4; ++k) {
    int c = c0 + ty + k * 8;
    dst[(size_t)c * R + r0 + tx] = tile[tx][ty + k * 8] + bv;
  }
}

// ---- Kernel 4: filter FFT -> Kf_br[d][p] = rfft(k_d,16384)[br13(p)]/16384 ----
// p=0 packs (R[0], R[8192]) (both real).
__global__ __launch_bounds__(TPB, 2) void fftk_kernel(
    const float* __restrict__ kt, float2* __restrict__ Kf) {
  __shared__ float2 A[M];
  int tid = threadIdx.x;
  int d = blockIdx.x;
  fwd_fft(A, (const float2*)(kt + (size_t)d * L), tid);

  float2* Kfd = Kf + (size_t)d * M;
  const float sc = 1.0f / 16384.0f;
  #pragma unroll 4
  for (int i = 0; i < M / TPB; ++i) {
    int p = tid + i * TPB;
    if (p == 0) {
      float2 Z0 = A[PHYS(0)];
      Kfd[0] = make_float2(sc * (Z0.x + Z0.y), sc * (Z0.x - Z0.y));
    } else {
      int t = 31 - __clz(p);
      int q = (3 << t) - 1 - p;         // partner position (same dyadic block)
      float2 Zk = A[PHYS(p)], Zj = A[PHYS(q)];
      float2 Ze = make_float2(0.5f * (Zk.x + Zj.x), 0.5f * (Zk.y - Zj.y));
      float2 Zo = make_float2(0.5f * (Zk.y + Zj.y), -0.5f * (Zk.x - Zj.x));
      int k = brev13(p);
      float2 W = twiddle(-3.14159265358979323846f * (float)k / 8192.0f);
      float2 U = cadd(Ze, cmul(W, Zo));  // R_filt[k]
      Kfd[p] = make_float2(sc * U.x, sc * U.y);
    }
  }
}

// ---------------- Kernel 5: per-channel FFT conv (in-place over one batch slab xt[D][L]) ----------------
// Pointwise phase is pair-owned: work item j handles positions {p, q} (disjoint
// across items) -> reads and writes confined to one thread, no barrier, no
// carry registers. Launch bound (TPB,2): round-5's (TPB,4) capped VGPR at 64
// -> 183MB/dispatch scratch-spill writes, conv memory-bound at 45% HBM.
__global__ __launch_bounds__(TPB, 2) void conv_kernel(
    float* __restrict__ xt, const float2* __restrict__ Kf) {
  __shared__ float2 A[M];
  int tid = threadIdx.x;
  int d = blockIdx.x;
  float2* ch = (float2*)(xt + (size_t)d * L);

  fwd_fft(A, ch, tid);

  const float2* Kfd = Kf + (size_t)d * M;
  #pragma unroll 2
  for (int i = 0; i < (M / 2) / TPB; ++i) {
    int j = tid + i * TPB;               // work item 0..4095
    if (j == 0) {
      // p = 0: packed (DC, Nyquist-of-16384), both real
      float2 Z0 = A[PHYS(0)];
      float U0 = Z0.x + Z0.y, UM = Z0.x - Z0.y;
      float2 C0 = Kfd[0];
      float V0 = U0 * C0.x, VM = UM * C0.y;
      A[PHYS(0)] = make_float2(0.5f * (V0 + VM), -0.5f * (V0 - VM));
      // p = 1: self-conjugate bin k = 4096 (W = -i); both pair formulas reduce to Y
      float2 Z1 = A[PHYS(1)];
      A[PHYS(1)] = cmul(conj2(Z1), Kfd[1]);
    } else {
      int hb = 1 << (31 - __clz(j));     // top bit of j
      int m = j - hb;
      int p = (hb << 1) + m;             // first half of dyadic block
      int q = (hb << 2) - 1 - m;         // Hermitian partner, second half
      float2 Zk = A[PHYS(p)], Zj = A[PHYS(q)];
      float2 Ze = make_float2(0.5f * (Zk.x + Zj.x), 0.5f * (Zk.y - Zj.y));
      float2 Zo = make_float2(0.5f * (Zk.y + Zj.y), -0.5f * (Zk.x - Zj.x));
      int k = brev13(p);
      float2 W = twiddle(-3.14159265358979323846f * (float)k / 8192.0f);
      float2 WZo = cmul(W, Zo);
      float2 Uk  = cadd(Ze, WZo);        // R_x[k]
      float2 Umc = csub(Ze, WZo);        // conj(R_x[M-k])
      float2 Ck = Kfd[p], Cj = Kfd[q];
      float2 Vk  = cmul(Uk, Ck);         // Y[k]
      float2 VjC = cmul(Umc, conj2(Cj)); // conj(Y[M-k])
      float2 Ye = make_float2(0.5f * (Vk.x + VjC.x), 0.5f * (Vk.y + VjC.y));
      float2 G  = make_float2(0.5f * (Vk.x - VjC.x), 0.5f * (Vk.y - VjC.y));
      float2 Yo = cmul(conj2(W), G);
      A[PHYS(p)] = make_float2(Ye.x - Yo.y, -(Ye.y + Yo.x));  // conj(Z'[k])
      A[PHYS(q)] = make_float2(Ye.x + Yo.y, Ye.y - Yo.x);     // conj(Z'[M-k])
    }
  }
  __syncthreads();

  // inverse via DIT on conj'd spectrum (bitrev layout is exactly DIT input)
  r8_round<0, false>(A, tid);
  __syncthreads();
  r8_round<3, false>(A, tid);
  __syncthreads();
  r8_round<6, false>(A, tid);
  __syncthreads();

  // final radix-16 DIT (stages 9..12); only u<8 outputs needed (n < 4096)
  const float inv = 1.0f / (float)M;
  {
    int pos = tid;
    float2 xl[8], xh[8];
    #pragma unroll
    for (int u = 0; u < 8; ++u) xl[u] = A[PHYS(pos + (u << 9))];
    #pragma unroll
    for (int u = 0; u < 8; ++u) xh[u] = A[PHYS(pos + ((u + 8) << 9))];
    float2 v = twiddle(-6.2831853071795864769f * (float)pos / 8192.0f);
    float2 v2 = csq(v), v4 = csq(v2), v8 = csq(v4);
    r8_dit(xl, v2, v4, v8);
    r8_dit(xh, v2, v4, v8);
    #pragma unroll
    for (int u = 0; u < 8; ++u) {
      float2 F = cadd(xl[u], cmul(cmul(v, W16C[u]), xh[u]));
      ch[pos + (u << 9)] = make_float2(F.x * inv, -F.y * inv);
    }
  }
}

extern "C" void kernel_launch(void* const* d_in, const int* in_sizes, int n_in,
                              void* d_out, int out_size, void* d_ws, size_t ws_size,
                              hipStream_t stream) {
  const float* x      = (const float*)d_in[0];
  const float* w0     = (const float*)d_in[1];
  const float* b0     = (const float*)d_in[2];
  const float* w1     = (const float*)d_in[3];
  const float* b1     = (const float*)d_in[4];
  const float* w2     = (const float*)d_in[5];
  const float* b2     = (const float*)d_in[6];
  const float* freq   = (const float*)d_in[7];
  const float* deltas = (const float*)d_in[8];
  const float* bias   = (const float*)d_in[9];
  float* out = (float*)d_out;

  // workspace layout (74 MB): [S: 2 MB][Kf: 48 MB][slab: 24 MB]
  // slab = kt until fftk consumes it, then per-batch transposed-x buffer.
  float*  S    = (float*)d_ws;
  float2* Kf   = (float2*)(S + (size_t)L * 64);
  float*  slab = (float*)(Kf + (size_t)DCH * M);

  mlp_kernel<<<128, 256, 0, stream>>>(w0, b0, w1, b1, freq, S);
  kfilter_kernel<<<dim3(128, 48), 256, 0, stream>>>(S, w2, b2, deltas, slab);
  fftk_kernel<<<DCH, TPB, 0, stream>>>(slab, Kf);

  for (int b = 0; b < BATCH; ++b) {
    const float* xb = x + (size_t)b * L * DCH;
    float* ob = out + (size_t)b * L * DCH;
    transpose_kernel<<<dim3(DCH / 32, L / 32), dim3(32, 8), 0, stream>>>(
        xb, slab, L, DCH, nullptr);
    conv_kernel<<<DCH, TPB, 0, stream>>>(slab, Kf);
    transpose_kernel<<<dim3(L / 32, DCH / 32), dim3(32, 8), 0, stream>>>(
        slab, ob, DCH, L, bias);
  }
}